// Round 10
// baseline (818.457 us; speedup 1.0000x reference)
//
#include <hip/hip_runtime.h>
#include <hip/hip_fp16.h>
#include <hip/hip_cooperative_groups.h>

namespace cg = cooperative_groups;

#define N_NODES 50000
#define DIM 128
#define NEDGE 800000
#define NGRAPH 100
#define NPG 500      // nodes per graph
#define NBUCKET 250  // dst buckets
#define NPB 200      // nodes per bucket
#define BCAP 4096    // padded slots per bucket
#define CHUNK 2048   // edges per scatter chunk
#define EPT (CHUNK / 256)
#define G1TILES 782  // ceil(50000 / 64) 64-row gemm tiles (256 thr = 4 waves x 16 rows)
#define SCAT_CHUNKS 391  // ceil(800000 / 2048)

typedef _Float16 f16x8 __attribute__((ext_vector_type(8)));
typedef float f32x4 __attribute__((ext_vector_type(4)));
typedef float f32x2 __attribute__((ext_vector_type(2)));

// ---------------- fp8 helpers (OCP e4m3 HW converts) ----------------
__device__ inline float wgt(unsigned p) {
    return __half2float(__ushort_as_half((unsigned short)(p & 0xffffu)));
}
__device__ inline void accrow(uint2 q, float w, float* acc) {
    f32x2 f;
    f = __builtin_amdgcn_cvt_pk_f32_fp8((int)q.x, false); acc[0] = fmaf(w, f[0], acc[0]); acc[1] = fmaf(w, f[1], acc[1]);
    f = __builtin_amdgcn_cvt_pk_f32_fp8((int)q.x, true);  acc[2] = fmaf(w, f[0], acc[2]); acc[3] = fmaf(w, f[1], acc[3]);
    f = __builtin_amdgcn_cvt_pk_f32_fp8((int)q.y, false); acc[4] = fmaf(w, f[0], acc[4]); acc[5] = fmaf(w, f[1], acc[5]);
    f = __builtin_amdgcn_cvt_pk_f32_fp8((int)q.y, true);  acc[6] = fmaf(w, f[0], acc[6]); acc[7] = fmaf(w, f[1], acc[7]);
}
__device__ inline unsigned pack_fp8x4(float a, float b, float c, float d) {
    int v = __builtin_amdgcn_cvt_pk_fp8_f32(a, b, 0, false);
    v = __builtin_amdgcn_cvt_pk_fp8_f32(c, d, v, true);
    return (unsigned)v;
}

// ---------------- MFMA fragment loads ----------------
__device__ inline f16x8 load_afrag_f32(const float* a) {
    float4 u0 = *(const float4*)a;
    float4 u1 = *(const float4*)(a + 4);
    f16x8 r;
    r[0] = (_Float16)u0.x; r[1] = (_Float16)u0.y; r[2] = (_Float16)u0.z; r[3] = (_Float16)u0.w;
    r[4] = (_Float16)u1.x; r[5] = (_Float16)u1.y; r[6] = (_Float16)u1.z; r[7] = (_Float16)u1.w;
    return r;
}
__device__ inline f16x8 load_afrag_fp8(const unsigned char* a) {
    uint2 q = *(const uint2*)a;
    f32x2 f0 = __builtin_amdgcn_cvt_pk_f32_fp8((int)q.x, false);
    f32x2 f1 = __builtin_amdgcn_cvt_pk_f32_fp8((int)q.x, true);
    f32x2 f2 = __builtin_amdgcn_cvt_pk_f32_fp8((int)q.y, false);
    f32x2 f3 = __builtin_amdgcn_cvt_pk_f32_fp8((int)q.y, true);
    f16x8 r;
    r[0] = (_Float16)f0[0]; r[1] = (_Float16)f0[1]; r[2] = (_Float16)f1[0]; r[3] = (_Float16)f1[1];
    r[4] = (_Float16)f2[0]; r[5] = (_Float16)f2[1]; r[6] = (_Float16)f3[0]; r[7] = (_Float16)f3[1];
    return r;
}

// one 64-row gemm tile: 4 waves x 16 rows; B-frags read from global (L1-hot 32 KB)
template <typename TIN>
__device__ inline void gemm_tile(const TIN* __restrict__ A, const _Float16* __restrict__ fragW,
                                 unsigned char* __restrict__ C, int tile, int t) {
    const int lane = t & 63;
    const int wid = t >> 6;
    const int row0 = tile * 64 + wid * 16;
    if (row0 >= N_NODES) return;
    const int arow = row0 + (lane & 15);
    const int koff = (lane >> 4) << 3;
    f32x4 acc[8] = {};
#pragma unroll
    for (int kt = 0; kt < 4; ++kt) {
        f16x8 a;
        const TIN* ap = A + (size_t)arow * DIM + kt * 32 + koff;
        if constexpr (sizeof(TIN) == 4) a = load_afrag_f32((const float*)ap);
        else                            a = load_afrag_fp8((const unsigned char*)ap);
#pragma unroll
        for (int nt = 0; nt < 8; ++nt) {
            f16x8 b = *(const f16x8*)&fragW[(((nt << 2) | kt) << 9) | (lane << 3)];
            acc[nt] = __builtin_amdgcn_mfma_f32_16x16x32_f16(a, b, acc[nt], 0, 0, 0);
        }
    }
    const int crow = row0 + ((lane >> 4) << 2);
    const int ccol = lane & 15;
#pragma unroll
    for (int nt = 0; nt < 8; ++nt) {
#pragma unroll
        for (int r = 0; r < 4; ++r) {
            int v8 = __builtin_amdgcn_cvt_pk_fp8_f32(acc[nt][r], acc[nt][r], 0, false);
            C[(size_t)(crow + r) * DIM + (nt << 4) + ccol] = (unsigned char)(v8 & 0xff);
        }
    }
}

// ---------------- scatter one 2048-edge chunk (LDS hist + run reservation) -
__device__ inline void scatter_chunk(const int* __restrict__ src, const int* __restrict__ dst,
                                     const float* __restrict__ w, int* __restrict__ gCur,
                                     uint2* __restrict__ stage, int c, int t,
                                     int* hist, int* base) {
    for (int i = t; i < NBUCKET; i += 256) hist[i] = 0;
    __syncthreads();
    const int e0 = c * CHUNK;
    int myDst[EPT];
#pragma unroll
    for (int j = 0; j < EPT; ++j) {
        int e = e0 + j * 256 + t;
        int d = (e < NEDGE) ? dst[e] : -1;
        myDst[j] = d;
        if (d >= 0) atomicAdd(&hist[d / NPB], 1);
    }
    __syncthreads();
    for (int i = t; i < NBUCKET; i += 256)
        base[i] = atomicAdd(&gCur[i], hist[i]);
    __syncthreads();
#pragma unroll
    for (int j = 0; j < EPT; ++j) {
        int d = myDst[j];
        if (d >= 0) {
            int e = e0 + j * 256 + t;
            int bk = d / NPB;
            int p = atomicAdd(&base[bk], 1);
            unsigned short wh = __half_as_ushort(__float2half_rn(w[e]));
            stage[p] = make_uint2(((unsigned)src[e] << 16) | (unsigned)wh,
                                  (unsigned)(d - bk * NPB));
        }
    }
    __syncthreads();
}

// ---------------- build one bucket's local CSR (256 thr, 16 items each) ----
__device__ inline void build_bucket(const int* __restrict__ gCur, const uint2* __restrict__ stage,
                                    unsigned* __restrict__ pack, int2* __restrict__ range,
                                    int bk, int t, int* lhist, int* lincl, int* lcur) {
    const int cnt = gCur[bk] - bk * BCAP;
    for (int i = t; i < NPB; i += 256) lhist[i] = 0;
    __syncthreads();
    unsigned myX[16];
    int myLd[16];
#pragma unroll
    for (int j = 0; j < 16; ++j) {
        int i = j * 256 + t;
        if (i < cnt) {
            uint2 r = stage[bk * BCAP + i];
            myX[j] = r.x;
            myLd[j] = (int)r.y;
            atomicAdd(&lhist[r.y], 1);
        } else {
            myLd[j] = -1;
        }
    }
    __syncthreads();
    int h = (t < NPB) ? lhist[t] : 0;
    lincl[t] = h;
    __syncthreads();
    for (int off = 1; off < 256; off <<= 1) {
        int v = (t >= off) ? lincl[t - off] : 0;
        __syncthreads();
        lincl[t] += v;
        __syncthreads();
    }
    if (t < NPB) lcur[t] = lincl[t] - h;
    __syncthreads();
#pragma unroll
    for (int j = 0; j < 16; ++j) {
        if (myLd[j] >= 0) {
            int p = atomicAdd(&lcur[myLd[j]], 1);
            pack[bk * BCAP + p] = myX[j];
        }
    }
    if (t < NPB)
        range[bk * NPB + t] = make_int2(bk * BCAP + lincl[t] - h, bk * BCAP + lincl[t]);
    __syncthreads();
}

// ---------------- gather one node (16 lanes, 8-deep unroll, fp8 msg) -------
template <int MODE>
__device__ inline void gather_node(const unsigned char* __restrict__ msg,
                                   const unsigned* __restrict__ pack,
                                   const int2* __restrict__ range,
                                   const float* __restrict__ bias,
                                   const float* __restrict__ wf,
                                   unsigned char* __restrict__ outF,
                                   float* __restrict__ outS, int grp, int lane) {
    int2 r = range[grp];
    int beg = r.x, end = r.y;
    float acc[8] = {};
    int i = beg;
    for (; i + 7 < end; i += 8) {
        unsigned p[8];
        uint2 q[8];
#pragma unroll
        for (int j = 0; j < 8; ++j) p[j] = pack[i + j];
#pragma unroll
        for (int j = 0; j < 8; ++j)
            q[j] = ((const uint2*)(msg + (size_t)(p[j] >> 16) * DIM))[lane];
#pragma unroll
        for (int j = 0; j < 8; ++j) accrow(q[j], wgt(p[j]), acc);
    }
    for (; i + 3 < end; i += 4) {
        unsigned p0 = pack[i], p1 = pack[i + 1], p2 = pack[i + 2], p3 = pack[i + 3];
        uint2 q0 = ((const uint2*)(msg + (size_t)(p0 >> 16) * DIM))[lane];
        uint2 q1 = ((const uint2*)(msg + (size_t)(p1 >> 16) * DIM))[lane];
        uint2 q2 = ((const uint2*)(msg + (size_t)(p2 >> 16) * DIM))[lane];
        uint2 q3 = ((const uint2*)(msg + (size_t)(p3 >> 16) * DIM))[lane];
        accrow(q0, wgt(p0), acc);
        accrow(q1, wgt(p1), acc);
        accrow(q2, wgt(p2), acc);
        accrow(q3, wgt(p3), acc);
    }
    for (; i < end; ++i) {
        unsigned p = pack[i];
        uint2 q = ((const uint2*)(msg + (size_t)(p >> 16) * DIM))[lane];
        accrow(q, wgt(p), acc);
    }
    float4 b0 = ((const float4*)bias)[2 * lane];
    float4 b1 = ((const float4*)bias)[2 * lane + 1];
    acc[0] = fmaxf(acc[0] + b0.x, 0.f); acc[1] = fmaxf(acc[1] + b0.y, 0.f);
    acc[2] = fmaxf(acc[2] + b0.z, 0.f); acc[3] = fmaxf(acc[3] + b0.w, 0.f);
    acc[4] = fmaxf(acc[4] + b1.x, 0.f); acc[5] = fmaxf(acc[5] + b1.y, 0.f);
    acc[6] = fmaxf(acc[6] + b1.z, 0.f); acc[7] = fmaxf(acc[7] + b1.w, 0.f);
    if (MODE == 0) {
        uint2 o;
        o.x = pack_fp8x4(acc[0], acc[1], acc[2], acc[3]);
        o.y = pack_fp8x4(acc[4], acc[5], acc[6], acc[7]);
        ((uint2*)(outF + (size_t)grp * DIM))[lane] = o;
    } else {
        float4 f0 = ((const float4*)wf)[2 * lane];
        float4 f1 = ((const float4*)wf)[2 * lane + 1];
        float d = acc[0] * f0.x + acc[1] * f0.y + acc[2] * f0.z + acc[3] * f0.w
                + acc[4] * f1.x + acc[5] * f1.y + acc[6] * f1.z + acc[7] * f1.w;
#pragma unroll
        for (int off = 8; off; off >>= 1) d += __shfl_down(d, off, 16);
        if (lane == 0) outS[grp] = d;
    }
}

// ---------------- per-graph readout ----------------
__device__ inline void readout_graph(const float* __restrict__ s, const unsigned* __restrict__ pack,
                                     const int2* __restrict__ range, const float* __restrict__ bfp,
                                     float* __restrict__ out, int g, int t, float* red) {
    float bf = bfp[0];
    float sum = 0.f;
    for (int n = t; n < NPG; n += 256) {
        int v = g * NPG + n;
        int2 r = range[v];
        float a = 0.f;
        for (int i = r.x; i < r.y; ++i) {
            unsigned p = pack[i];
            a += wgt(p) * s[p >> 16];
        }
        a += bf;
        sum += 1.f / (1.f + expf(-a));
    }
    red[t] = sum;
    __syncthreads();
    for (int k = 128; k > 0; k >>= 1) {
        if (t < k) red[t] += red[t + k];
        __syncthreads();
    }
    if (t == 0) out[g] = red[0] / (float)NPG;
    __syncthreads();
}

// ---------------- the persistent cooperative mega-kernel ----------------
__global__ __launch_bounds__(256, 8) void mega(
        const float* __restrict__ X, const float* __restrict__ ew,
        const float* __restrict__ W1, const float* __restrict__ b1,
        const float* __restrict__ W2, const float* __restrict__ b2,
        const float* __restrict__ Wf, const float* __restrict__ bf,
        const int* __restrict__ src, const int* __restrict__ dst,
        unsigned char* __restrict__ bufA, unsigned char* __restrict__ bufB,
        uint2* __restrict__ stage, unsigned* __restrict__ pack,
        int2* __restrict__ range, int* __restrict__ gCur,
        _Float16* __restrict__ fragW1, _Float16* __restrict__ fragW2,
        float* __restrict__ s_node, float* __restrict__ out) {
    cg::grid_group grid = cg::this_grid();
    const int nB = gridDim.x;
    const int b = blockIdx.x;
    const int t = threadIdx.x;
    __shared__ int shbuf[NPB + 256 + NPB];   // 2.6 KB, aliased per phase
    int* hist = shbuf;                // scatter: hist[250]
    int* base = shbuf + NBUCKET;      //          base[250]
    int* lhist = shbuf;               // build:   lhist[200]
    int* lincl = shbuf + NPB;         //          lincl[256]
    int* lcur  = shbuf + NPB + 256;   //          lcur[200]
    float* red = (float*)shbuf;       // readout: red[256]

    // ---- P0: init gCur + both pre-swizzled W-fragment images ----
    for (int i = b * 256 + t; i < 32768 + NBUCKET; i += nB * 256) {
        if (i < 32768) {
            int idx = i & 16383;
            const float* W = (i < 16384) ? W1 : W2;
            _Float16* F = (i < 16384) ? fragW1 : fragW2;
            int j = idx & 7, l = (idx >> 3) & 63, kt = (idx >> 9) & 3, nt = idx >> 11;
            int k = kt * 32 + ((l >> 4) << 3) + j;
            int col = (nt << 4) + (l & 15);
            F[idx] = (_Float16)W[k * DIM + col];
        } else {
            int bb = i - 32768;
            gCur[bb] = bb * BCAP;
        }
    }
    grid.sync();

    // ---- P1: gemm1 (X@W1 -> bufA fp8)  ||  bucket_scatter ----
    {
        int split = min(G1TILES, (nB * 2) / 3);
        if (split < 1) split = 1;
        if (b < split) {
            for (int tile = b; tile < G1TILES; tile += split)
                gemm_tile<float>(X, fragW1, bufA, tile, t);
        } else {
            for (int c = b - split; c < SCAT_CHUNKS; c += nB - split)
                scatter_chunk(src, dst, ew, gCur, stage, c, t, hist, base);
        }
    }
    grid.sync();

    // ---- P2: per-bucket local CSR build ----
    for (int bk = b; bk < NBUCKET; bk += nB)
        build_bucket(gCur, stage, pack, range, bk, t, lhist, lincl, lcur);
    grid.sync();

    // ---- P3: gather0: h1 = relu(A(X@W1)+b1) -> bufB fp8 ----
    for (int grp = b * 16 + (t >> 4); grp < N_NODES; grp += nB * 16)
        gather_node<0>(bufA, pack, range, b1, nullptr, bufB, nullptr, grp, t & 15);
    grid.sync();

    // ---- P4: gemm2: h1@W2 -> bufA fp8 ----
    for (int tile = b; tile < G1TILES; tile += nB)
        gemm_tile<unsigned char>(bufB, fragW2, bufA, tile, t);
    grid.sync();

    // ---- P5: gather1: s = relu(A(h1@W2)+b2)@Wf -> s_node ----
    for (int grp = b * 16 + (t >> 4); grp < N_NODES; grp += nB * 16)
        gather_node<1>(bufA, pack, range, b2, Wf, nullptr, s_node, grp, t & 15);
    grid.sync();

    // ---- P6: final aggregation + per-graph mean sigmoid ----
    for (int g = b; g < NGRAPH; g += nB)
        readout_graph(s_node, pack, range, bf, out, g, t, red);
}

extern "C" void kernel_launch(void* const* d_in, const int* in_sizes, int n_in,
                              void* d_out, int out_size, void* d_ws, size_t ws_size,
                              hipStream_t stream) {
    const float* X  = (const float*)d_in[0];
    const float* ew = (const float*)d_in[1];
    const float* W1 = (const float*)d_in[2];
    const float* b1 = (const float*)d_in[3];
    const float* W2 = (const float*)d_in[4];
    const float* b2 = (const float*)d_in[5];
    const float* Wf = (const float*)d_in[6];
    const float* bf = (const float*)d_in[7];
    const int* ei   = (const int*)d_in[8];
    const int* src  = ei;
    const int* dst  = ei + NEDGE;
    float* out = (float*)d_out;

    // workspace layout
    char* ws = (char*)d_ws;
    size_t off = 0;
    unsigned char* bufA = (unsigned char*)(ws + off); off += (size_t)N_NODES * DIM;   // 6.4 MB
    unsigned char* bufB = (unsigned char*)(ws + off); off += (size_t)N_NODES * DIM;   // 6.4 MB
    uint2* stage = (uint2*)(ws + off);  off += (size_t)NBUCKET * BCAP * 8;            // 8 MB
    unsigned* pack = (unsigned*)(ws + off); off += (size_t)NBUCKET * BCAP * 4;        // 4 MB
    int2* range = (int2*)(ws + off);    off += (size_t)N_NODES * 8;                   // 400 KB
    int* gCur   = (int*)(ws + off);     off += (size_t)256 * 4;
    _Float16* fragW1 = (_Float16*)(ws + off); off += (size_t)16384 * 2;               // 32 KB
    _Float16* fragW2 = (_Float16*)(ws + off); off += (size_t)16384 * 2;               // 32 KB
    float* s_node = (float*)(ws + off); off += (size_t)N_NODES * 4;

    // deterministic, capture-safe occupancy sizing
    int nbPerCU = 0;
    hipOccupancyMaxActiveBlocksPerMultiprocessor(&nbPerCU, mega, 256, 0);
    if (nbPerCU < 1) nbPerCU = 1;
    if (nbPerCU > 8) nbPerCU = 8;
    int dev = 0, numCU = 256;
    hipGetDevice(&dev);
    hipDeviceGetAttribute(&numCU, hipDeviceAttributeMultiprocessorCount, dev);
    if (numCU < 1) numCU = 256;
    int gridBlocks = nbPerCU * numCU;
    if (gridBlocks > 2048) gridBlocks = 2048;

    void* args[] = {
        (void*)&X, (void*)&ew, (void*)&W1, (void*)&b1, (void*)&W2, (void*)&b2,
        (void*)&Wf, (void*)&bf, (void*)&src, (void*)&dst,
        (void*)&bufA, (void*)&bufB, (void*)&stage, (void*)&pack, (void*)&range,
        (void*)&gCur, (void*)&fragW1, (void*)&fragW2, (void*)&s_node, (void*)&out};
    hipLaunchCooperativeKernel((const void*)mega, dim3(gridBlocks), dim3(256),
                               args, 0, stream);
}

// Round 11
// 99.022 us; speedup vs baseline: 8.2654x; 8.2654x over previous
//
#include <hip/hip_runtime.h>
#include <hip/hip_fp16.h>

#define N_NODES 50000
#define DIM 128
#define NEDGE 800000
#define NGRAPH 100
#define NPG 500      // nodes per graph
#define NBUCKET 250  // dst buckets
#define NPB 200      // nodes per bucket
#define BCAP 4096    // padded slots per bucket
#define CHUNK 2048   // edges per scatter chunk
#define EPT (CHUNK / 256)

typedef _Float16 f16x8 __attribute__((ext_vector_type(8)));
typedef float f32x4 __attribute__((ext_vector_type(4)));
typedef float f32x2 __attribute__((ext_vector_type(2)));

// ---------------- fp8 helpers (OCP e4m3 HW converts) ----------------
__device__ inline float wgt(unsigned p) {
    return __half2float(__ushort_as_half((unsigned short)(p & 0xffffu)));
}
__device__ inline void accrow(uint2 q, float w, float* acc) {
    f32x2 f;
    f = __builtin_amdgcn_cvt_pk_f32_fp8((int)q.x, false); acc[0] = fmaf(w, f[0], acc[0]); acc[1] = fmaf(w, f[1], acc[1]);
    f = __builtin_amdgcn_cvt_pk_f32_fp8((int)q.x, true);  acc[2] = fmaf(w, f[0], acc[2]); acc[3] = fmaf(w, f[1], acc[3]);
    f = __builtin_amdgcn_cvt_pk_f32_fp8((int)q.y, false); acc[4] = fmaf(w, f[0], acc[4]); acc[5] = fmaf(w, f[1], acc[5]);
    f = __builtin_amdgcn_cvt_pk_f32_fp8((int)q.y, true);  acc[6] = fmaf(w, f[0], acc[6]); acc[7] = fmaf(w, f[1], acc[7]);
}
__device__ inline unsigned pack_fp8x4(float a, float b, float c, float d) {
    int v = __builtin_amdgcn_cvt_pk_fp8_f32(a, b, 0, false);
    v = __builtin_amdgcn_cvt_pk_fp8_f32(c, d, v, true);
    return (unsigned)v;
}

// ---------------- prep: cursor init + pre-swizzled fp16 W-fragments -------
__global__ void prep(const float* __restrict__ W1, const float* __restrict__ W2,
                     _Float16* __restrict__ fragW1, _Float16* __restrict__ fragW2,
                     int* __restrict__ gCur) {
    const int b = blockIdx.x;
    if (b == 128) {
        int t = threadIdx.x;
        if (t < NBUCKET) gCur[t] = t * BCAP;
        return;
    }
    const float* W = (b < 64) ? W1 : W2;
    _Float16* F = (b < 64) ? fragW1 : fragW2;
    int idx = (b & 63) * 256 + threadIdx.x;   // 0..16383
    int j = idx & 7, l = (idx >> 3) & 63, kt = (idx >> 9) & 3, nt = idx >> 11;
    int k = kt * 32 + ((l >> 4) << 3) + j;
    int col = (nt << 4) + (l & 15);
    F[idx] = (_Float16)W[k * DIM + col];
}

// ---------------- pass 1: bucket edges by dst/NPB --------------
__global__ void bucket_scatter(const int* __restrict__ src, const int* __restrict__ dst,
                               const float* __restrict__ w, int* __restrict__ gCur,
                               uint2* __restrict__ stage, int E) {
    __shared__ int hist[NBUCKET];
    __shared__ int base[NBUCKET];
    for (int i = threadIdx.x; i < NBUCKET; i += 256) hist[i] = 0;
    __syncthreads();
    const int e0 = blockIdx.x * CHUNK;
    int myDst[EPT];
#pragma unroll
    for (int j = 0; j < EPT; ++j) {
        int e = e0 + j * 256 + threadIdx.x;
        int d = (e < E) ? dst[e] : -1;
        myDst[j] = d;
        if (d >= 0) atomicAdd(&hist[d / NPB], 1);
    }
    __syncthreads();
    for (int i = threadIdx.x; i < NBUCKET; i += 256)
        base[i] = atomicAdd(&gCur[i], hist[i]);   // reserve private run
    __syncthreads();
#pragma unroll
    for (int j = 0; j < EPT; ++j) {
        int d = myDst[j];
        if (d >= 0) {
            int e = e0 + j * 256 + threadIdx.x;
            int b = d / NPB;
            int p = atomicAdd(&base[b], 1);
            unsigned short wh = __half_as_ushort(__float2half_rn(w[e]));
            stage[p] = make_uint2(((unsigned)src[e] << 16) | (unsigned)wh,
                                  (unsigned)(d - b * NPB));
        }
    }
}

// ---------------- MFMA fragment loads ----------------
__device__ inline f16x8 load_afrag_f32(const float* a) {
    float4 u0 = *(const float4*)a;
    float4 u1 = *(const float4*)(a + 4);
    f16x8 r;
    r[0] = (_Float16)u0.x; r[1] = (_Float16)u0.y; r[2] = (_Float16)u0.z; r[3] = (_Float16)u0.w;
    r[4] = (_Float16)u1.x; r[5] = (_Float16)u1.y; r[6] = (_Float16)u1.z; r[7] = (_Float16)u1.w;
    return r;
}

// one 128-row gemm tile from fp32 A, fragW in LDS (8 waves x 16 rows)
__device__ inline void gemm_tile_f32(const float* __restrict__ A, const _Float16* fragW,
                                     unsigned char* __restrict__ C, int blk, int tid) {
    const int lane = tid & 63;
    const int wid = tid >> 6;
    const int row0 = blk * 128 + wid * 16;
    if (row0 >= N_NODES) return;
    const int arow = row0 + (lane & 15);
    const int koff = (lane >> 4) << 3;
    f32x4 acc[8] = {};
#pragma unroll
    for (int kt = 0; kt < 4; ++kt) {
        f16x8 a = load_afrag_f32(A + (size_t)arow * DIM + kt * 32 + koff);
#pragma unroll
        for (int nt = 0; nt < 8; ++nt) {
            f16x8 b = *(const f16x8*)&fragW[(((nt << 2) | kt) << 9) | (lane << 3)];
            acc[nt] = __builtin_amdgcn_mfma_f32_16x16x32_f16(a, b, acc[nt], 0, 0, 0);
        }
    }
    const int crow = row0 + ((lane >> 4) << 2);
    const int ccol = lane & 15;
#pragma unroll
    for (int nt = 0; nt < 8; ++nt) {
#pragma unroll
        for (int r = 0; r < 4; ++r) {
            int v8 = __builtin_amdgcn_cvt_pk_fp8_f32(acc[nt][r], acc[nt][r], 0, false);
            C[(size_t)(crow + r) * DIM + (nt << 4) + ccol] = (unsigned char)(v8 & 0xff);
        }
    }
}

// ---------------- fused: gemm1 (blocks < MB) + bucket_build (blocks >= MB) -
#define MFMA_BLK ((N_NODES + 127) / 128)   // 391
__global__ __launch_bounds__(512) void gemm1_build(
        const float* __restrict__ A, const _Float16* __restrict__ fragWg,
        unsigned char* __restrict__ C, const int* __restrict__ gCur,
        const uint2* __restrict__ stage, unsigned int* __restrict__ pack,
        int2* __restrict__ range) {
    __shared__ __align__(16) _Float16 fragW[16384];   // 32 KB (gemm path)
    __shared__ int lhist[NPB];
    __shared__ int lincl[256];
    __shared__ int lcur[NPB];
    const int tid = threadIdx.x;
    if (blockIdx.x < MFMA_BLK) {
        for (int i = tid; i < 2048; i += 512)
            ((uint4*)fragW)[i] = ((const uint4*)fragWg)[i];
        __syncthreads();
        gemm_tile_f32(A, fragW, C, blockIdx.x, tid);
        return;
    }
    // ---- bucket_build path (512 threads, 8 items each) ----
    const int b = blockIdx.x - MFMA_BLK;
    const int t = tid;
    const int cnt = gCur[b] - b * BCAP;
    for (int i = t; i < NPB; i += 512) lhist[i] = 0;
    __syncthreads();
    unsigned myX[BCAP / 512];
    int myLd[BCAP / 512];
#pragma unroll
    for (int j = 0; j < BCAP / 512; ++j) {
        int i = j * 512 + t;
        if (i < cnt) {
            uint2 r = stage[b * BCAP + i];
            myX[j] = r.x;
            myLd[j] = (int)r.y;
            atomicAdd(&lhist[r.y], 1);
        } else {
            myLd[j] = -1;
        }
    }
    __syncthreads();
    int h = (t < NPB) ? lhist[t] : 0;
    if (t < 256) lincl[t] = h;
    __syncthreads();
    for (int off = 1; off < 256; off <<= 1) {
        int v = (t >= off && t < 256) ? lincl[t - off] : 0;
        __syncthreads();
        if (t < 256) lincl[t] += v;
        __syncthreads();
    }
    if (t < NPB) lcur[t] = lincl[t] - h;   // exclusive prefix
    __syncthreads();
#pragma unroll
    for (int j = 0; j < BCAP / 512; ++j) {
        if (myLd[j] >= 0) {
            int p = atomicAdd(&lcur[myLd[j]], 1);
            pack[b * BCAP + p] = myX[j];
        }
    }
    if (t < NPB) {
        int v = b * NPB + t;
        range[v] = make_int2(b * BCAP + lincl[t] - h, b * BCAP + lincl[t]);
    }
}

// ---------------- fused gather0 + gemm2 ----------------
// Block = 16 consecutive nodes. Phase A: 16 groups x 16 lanes gather
// h1 = relu(A(X@W1)+b1) -> LDS fp16 tile (XOR-swizzled rows).
// Phase B: 4 waves MFMA the 16x128 tile vs fragW2 (global, L1-hot) -> fp8 C.
__global__ __launch_bounds__(256) void gather_gemm2(
        const unsigned char* __restrict__ msg, const unsigned int* __restrict__ pack,
        const int2* __restrict__ range, const float* __restrict__ bias,
        const _Float16* __restrict__ fragW2, unsigned char* __restrict__ C) {
    __shared__ __align__(16) char hT[16 * 256];   // 16 rows x 128 fp16 (4 KB)
    const int t = threadIdx.x;
    const int grpL = t >> 4;       // local node 0..15
    const int lane16 = t & 15;
    const int tile = blockIdx.x;   // 3125 tiles x 16 nodes = 50000
    {
        const int grp = tile * 16 + grpL;
        int2 r = range[grp];
        int beg = r.x, end = r.y;
        float acc[8] = {};
        int i = beg;
        for (; i + 7 < end; i += 8) {
            unsigned p[8];
            uint2 q[8];
#pragma unroll
            for (int j = 0; j < 8; ++j) p[j] = pack[i + j];
#pragma unroll
            for (int j = 0; j < 8; ++j)
                q[j] = ((const uint2*)(msg + (size_t)(p[j] >> 16) * DIM))[lane16];
#pragma unroll
            for (int j = 0; j < 8; ++j) accrow(q[j], wgt(p[j]), acc);
        }
        for (; i + 3 < end; i += 4) {
            unsigned p0 = pack[i], p1 = pack[i + 1], p2 = pack[i + 2], p3 = pack[i + 3];
            uint2 q0 = ((const uint2*)(msg + (size_t)(p0 >> 16) * DIM))[lane16];
            uint2 q1 = ((const uint2*)(msg + (size_t)(p1 >> 16) * DIM))[lane16];
            uint2 q2 = ((const uint2*)(msg + (size_t)(p2 >> 16) * DIM))[lane16];
            uint2 q3 = ((const uint2*)(msg + (size_t)(p3 >> 16) * DIM))[lane16];
            accrow(q0, wgt(p0), acc);
            accrow(q1, wgt(p1), acc);
            accrow(q2, wgt(p2), acc);
            accrow(q3, wgt(p3), acc);
        }
        for (; i < end; ++i) {
            unsigned p = pack[i];
            uint2 q = ((const uint2*)(msg + (size_t)(p >> 16) * DIM))[lane16];
            accrow(q, wgt(p), acc);
        }
        float4 b0 = ((const float4*)bias)[2 * lane16];
        float4 b1 = ((const float4*)bias)[2 * lane16 + 1];
        union { __half2 h[4]; uint4 u; } o;
        o.h[0] = __floats2half2_rn(fmaxf(acc[0] + b0.x, 0.f), fmaxf(acc[1] + b0.y, 0.f));
        o.h[1] = __floats2half2_rn(fmaxf(acc[2] + b0.z, 0.f), fmaxf(acc[3] + b0.w, 0.f));
        o.h[2] = __floats2half2_rn(fmaxf(acc[4] + b1.x, 0.f), fmaxf(acc[5] + b1.y, 0.f));
        o.h[3] = __floats2half2_rn(fmaxf(acc[6] + b1.z, 0.f), fmaxf(acc[7] + b1.w, 0.f));
        int boff = (grpL << 8) | (lane16 << 4);
        boff ^= (grpL & 7) << 4;              // XOR swizzle (G4)
        *(uint4*)(hT + boff) = o.u;
    }
    __syncthreads();
    // ---- MFMA phase: wave wid handles nt = 2*wid, 2*wid+1 ----
    const int lane = t & 63;
    const int wid = t >> 6;
    const int arowL = lane & 15;
    const int koff = (lane >> 4) << 3;
    f32x4 acc2[2] = {};
#pragma unroll
    for (int kt = 0; kt < 4; ++kt) {
        int boff = (arowL << 8) | ((kt * 32 + koff) << 1);
        boff ^= (arowL & 7) << 4;
        f16x8 a = *(const f16x8*)(hT + boff);
#pragma unroll
        for (int n = 0; n < 2; ++n) {
            int nt = wid * 2 + n;
            f16x8 b = *(const f16x8*)&fragW2[(((nt << 2) | kt) << 9) | (lane << 3)];
            acc2[n] = __builtin_amdgcn_mfma_f32_16x16x32_f16(a, b, acc2[n], 0, 0, 0);
        }
    }
    const int crow = tile * 16 + ((lane >> 4) << 2);
    const int ccol = lane & 15;
#pragma unroll
    for (int n = 0; n < 2; ++n) {
#pragma unroll
        for (int r = 0; r < 4; ++r) {
            int v8 = __builtin_amdgcn_cvt_pk_fp8_f32(acc2[n][r], acc2[n][r], 0, false);
            C[(size_t)(crow + r) * DIM + ((wid * 2 + n) << 4) + ccol] = (unsigned char)(v8 & 0xff);
        }
    }
}

// ---------------- gather1: s = relu(A(h1@W2)+b2) @ Wf ----------------
__global__ void gather_wf(const unsigned char* __restrict__ msg,
                          const unsigned int* __restrict__ pack,
                          const int2* __restrict__ range, const float* __restrict__ bias,
                          const float* __restrict__ wf, float* __restrict__ outS) {
    int gid = blockIdx.x * blockDim.x + threadIdx.x;
    int grp = gid >> 4, lane = gid & 15;
    if (grp >= N_NODES) return;
    int2 r = range[grp];
    int beg = r.x, end = r.y;
    float acc[8] = {};
    int i = beg;
    for (; i + 7 < end; i += 8) {
        unsigned p[8];
        uint2 q[8];
#pragma unroll
        for (int j = 0; j < 8; ++j) p[j] = pack[i + j];
#pragma unroll
        for (int j = 0; j < 8; ++j)
            q[j] = ((const uint2*)(msg + (size_t)(p[j] >> 16) * DIM))[lane];
#pragma unroll
        for (int j = 0; j < 8; ++j) accrow(q[j], wgt(p[j]), acc);
    }
    for (; i + 3 < end; i += 4) {
        unsigned p0 = pack[i], p1 = pack[i + 1], p2 = pack[i + 2], p3 = pack[i + 3];
        uint2 q0 = ((const uint2*)(msg + (size_t)(p0 >> 16) * DIM))[lane];
        uint2 q1 = ((const uint2*)(msg + (size_t)(p1 >> 16) * DIM))[lane];
        uint2 q2 = ((const uint2*)(msg + (size_t)(p2 >> 16) * DIM))[lane];
        uint2 q3 = ((const uint2*)(msg + (size_t)(p3 >> 16) * DIM))[lane];
        accrow(q0, wgt(p0), acc);
        accrow(q1, wgt(p1), acc);
        accrow(q2, wgt(p2), acc);
        accrow(q3, wgt(p3), acc);
    }
    for (; i < end; ++i) {
        unsigned p = pack[i];
        uint2 q = ((const uint2*)(msg + (size_t)(p >> 16) * DIM))[lane];
        accrow(q, wgt(p), acc);
    }
    float4 b0 = ((const float4*)bias)[2 * lane];
    float4 b1 = ((const float4*)bias)[2 * lane + 1];
    float4 f0 = ((const float4*)wf)[2 * lane];
    float4 f1 = ((const float4*)wf)[2 * lane + 1];
    float d = fmaxf(acc[0] + b0.x, 0.f) * f0.x + fmaxf(acc[1] + b0.y, 0.f) * f0.y
            + fmaxf(acc[2] + b0.z, 0.f) * f0.z + fmaxf(acc[3] + b0.w, 0.f) * f0.w
            + fmaxf(acc[4] + b1.x, 0.f) * f1.x + fmaxf(acc[5] + b1.y, 0.f) * f1.y
            + fmaxf(acc[6] + b1.z, 0.f) * f1.z + fmaxf(acc[7] + b1.w, 0.f) * f1.w;
#pragma unroll
    for (int off = 8; off; off >>= 1) d += __shfl_down(d, off, 16);
    if (lane == 0) outS[grp] = d;
}

// ---------------- fused final aggregation + per-graph readout -------------
__global__ void final_readout(const float* __restrict__ s, const unsigned int* __restrict__ pack,
                              const int2* __restrict__ range, const float* __restrict__ bfp,
                              float* __restrict__ out) {
    __shared__ float red[256];
    int g = blockIdx.x;
    float bf = bfp[0];
    float sum = 0.f;
    for (int n = threadIdx.x; n < NPG; n += blockDim.x) {
        int v = g * NPG + n;
        int2 r = range[v];
        float a = 0.f;
        for (int i = r.x; i < r.y; ++i) {
            unsigned int p = pack[i];
            a += wgt(p) * s[p >> 16];
        }
        a += bf;
        sum += 1.f / (1.f + expf(-a));
    }
    red[threadIdx.x] = sum;
    __syncthreads();
    for (int t = 128; t > 0; t >>= 1) {
        if (threadIdx.x < t) red[threadIdx.x] += red[threadIdx.x + t];
        __syncthreads();
    }
    if (threadIdx.x == 0) out[g] = red[0] / (float)NPG;
}

extern "C" void kernel_launch(void* const* d_in, const int* in_sizes, int n_in,
                              void* d_out, int out_size, void* d_ws, size_t ws_size,
                              hipStream_t stream) {
    const float* X  = (const float*)d_in[0];
    const float* ew = (const float*)d_in[1];
    const float* W1 = (const float*)d_in[2];
    const float* b1 = (const float*)d_in[3];
    const float* W2 = (const float*)d_in[4];
    const float* b2 = (const float*)d_in[5];
    const float* Wf = (const float*)d_in[6];
    const float* bf = (const float*)d_in[7];
    const int* ei   = (const int*)d_in[8];
    const int* src  = ei;
    const int* dst  = ei + NEDGE;

    float* out = (float*)d_out;

    // workspace layout
    char* ws = (char*)d_ws;
    size_t off = 0;
    unsigned char* bufA = (unsigned char*)(ws + off); off += (size_t)N_NODES * DIM;  // 6.4 MB
    unsigned char* bufB = (unsigned char*)(ws + off); off += (size_t)N_NODES * DIM;  // 6.4 MB
    uint2* stage = (uint2*)(ws + off);  off += (size_t)NBUCKET * BCAP * 8;           // 8 MB
    unsigned int* pack = (unsigned int*)(ws + off); off += (size_t)NBUCKET * BCAP * 4; // 4 MB
    int2* range = (int2*)(ws + off);    off += (size_t)N_NODES * 8;                  // 400 KB
    int* gCur   = (int*)(ws + off);     off += (size_t)256 * 4;
    _Float16* fragW1 = (_Float16*)(ws + off); off += (size_t)16384 * 2;              // 32 KB
    _Float16* fragW2 = (_Float16*)(ws + off); off += (size_t)16384 * 2;              // 32 KB
    float* s_node = (float*)(ws + off); off += (size_t)N_NODES * 4;

    const int TB = 256;
    const int SCAT_BLK = (NEDGE + CHUNK - 1) / CHUNK;     // 391
    const int TILE_BLK = N_NODES / 16;                    // 3125
    const int GATHER_BLK = (N_NODES * 16 + TB - 1) / TB;  // 3125

    // ---- prep: cursors + pre-swizzled W fragments ----
    prep<<<129, TB, 0, stream>>>(W1, W2, fragW1, fragW2, gCur);
    // ---- CSR pass 1 ----
    bucket_scatter<<<SCAT_BLK, TB, 0, stream>>>(src, dst, ew, gCur, stage, NEDGE);
    // ---- layer-1 GEMM fused with CSR pass 2 (independent work) ----
    gemm1_build<<<MFMA_BLK + NBUCKET, 512, 0, stream>>>(X, fragW1, bufA, gCur,
                                                        stage, pack, range);
    // ---- fused: gather0 (h1) + gemm2 (h1@W2 -> bufB fp8) ----
    gather_gemm2<<<TILE_BLK, TB, 0, stream>>>(bufA, pack, range, b1, fragW2, bufB);
    // ---- gather1 + Wf dot -> s_node ----
    gather_wf<<<GATHER_BLK, TB, 0, stream>>>(bufB, pack, range, b2, Wf, s_node);
    // ---- final aggregation + readout (fused) ----
    final_readout<<<NGRAPH, TB, 0, stream>>>(s_node, pack, range, bf, out);
}